// Round 1
// baseline (1105.407 us; speedup 1.0000x reference)
//
#include <hip/hip_runtime.h>
#include <hip/hip_bf16.h>

// Problem constants (fixed by reference)
#define V_SZ 32000
#define KCTX 3
#define D_SZ 1024
#define S_SZ 2048
#define B_SZ 2
#define M_SZ (S_SZ * B_SZ)      // 4096 rows
#define KD   (KCTX * D_SZ)      // 3072

using bf16x8 = __attribute__((ext_vector_type(8))) __bf16;
using f32x4  = __attribute__((ext_vector_type(4))) float;

// ---------------------------------------------------------------------------
// Transpose + fp32->bf16 convert:  src (R x C, f32, row-major) -> dst (C x R, bf16)
// grid: (C/32, R/32), block: (32, 8)
// ---------------------------------------------------------------------------
__global__ void transpose_cvt(const float* __restrict__ src,
                              __hip_bfloat16* __restrict__ dst,
                              int R, int C) {
    __shared__ float tile[32][33];
    const int c0 = blockIdx.x * 32;
    const int r0 = blockIdx.y * 32;
    const int tx = threadIdx.x;   // 0..31
    const int ty = threadIdx.y;   // 0..7
#pragma unroll
    for (int j = ty; j < 32; j += 8)
        tile[j][tx] = src[(size_t)(r0 + j) * C + (c0 + tx)];
    __syncthreads();
#pragma unroll
    for (int j = ty; j < 32; j += 8)
        dst[(size_t)(c0 + j) * R + (r0 + tx)] = __float2bfloat16(tile[tx][j]);
}

// ---------------------------------------------------------------------------
// Context gather + convert: X[m][j*1024 + d] = bf16(emb[ctx(m,j)][d])
// ctx(m,j): m = t*B + b; token = tokens[(t-3+j)*B + b] or 0 if t-3+j < 0
// grid: M_SZ*KCTX blocks of 256; each block does one (m, j) row of 1024.
// ---------------------------------------------------------------------------
__global__ void gather_cvt(const int* __restrict__ tokens,
                           const float* __restrict__ emb,
                           __hip_bfloat16* __restrict__ X) {
    const int bid = blockIdx.x;
    const int m = bid / KCTX;
    const int j = bid - m * KCTX;
    const int t = m >> 1;
    const int b = m & 1;
    const int tj = t - KCTX + j;
    const int tok = (tj >= 0) ? tokens[tj * B_SZ + b] : 0;

    const float4 v = reinterpret_cast<const float4*>(emb + (size_t)tok * D_SZ)[threadIdx.x];
    __hip_bfloat16 o[4];
    o[0] = __float2bfloat16(v.x);
    o[1] = __float2bfloat16(v.y);
    o[2] = __float2bfloat16(v.z);
    o[3] = __float2bfloat16(v.w);
    __hip_bfloat16* dst = X + (size_t)m * KD + (size_t)j * D_SZ;
    reinterpret_cast<ushort4*>(dst)[threadIdx.x] = *reinterpret_cast<ushort4*>(o);
}

// ---------------------------------------------------------------------------
// bf16 MFMA GEMM, m97 structure: 128x128 tile, BK=64, 4 waves (2x2 of 64x64),
// global_load_lds width-16 staging, 2-barrier K-loop.
// A: M x K bf16 row-major.  BT: N x K bf16 row-major (B transposed).
// EPI==0: C = bf16( silu(acc + bias[n]) )     (GEMM1 -> H)
// EPI==1: C = f32 ( acc + bias[n] )           (GEMM2 -> logits)
// ---------------------------------------------------------------------------
#define TM 128
#define TN 128
#define TK 64

template <int EPI>
__global__ __launch_bounds__(256) void gemm_bt(
    const unsigned short* __restrict__ A,
    const unsigned short* __restrict__ BT,
    const float* __restrict__ bias,
    void* __restrict__ C, int M, int N, int K) {
    __shared__ unsigned short lsA[TM * TK];
    __shared__ unsigned short lsB[TN * TK];

    const int tid  = threadIdx.x;
    const int lane = tid & 63;
    const int w    = tid >> 6;          // wave 0..3
    const int wm   = (w >> 1) * 64;     // wave row offset in tile
    const int wn   = (w & 1) * 64;     // wave col offset in tile
    const int m0   = blockIdx.y * TM;
    const int n0   = blockIdx.x * TN;

    f32x4 acc[4][4] = {};

    for (int k0 = 0; k0 < K; k0 += TK) {
        __syncthreads();   // all waves done computing previous tile
        // ---- stage A and B tiles: 128 rows x 64 cols bf16 = 8 x 16B per row
#pragma unroll
        for (int i = 0; i < 4; ++i) {
            const int s = i * 256 + tid;     // segment id 0..1023
            const int r = s >> 3;            // tile row
            const int c = s & 7;             // 16B chunk in row
            const unsigned short* srcA = A + (size_t)(m0 + r) * K + k0 + c * 8;
            __builtin_amdgcn_global_load_lds(
                (const __attribute__((address_space(1))) void*)srcA,
                (__attribute__((address_space(3))) void*)(lsA + s * 8), 16, 0, 0);
            const unsigned short* srcB = BT + (size_t)(n0 + r) * K + k0 + c * 8;
            __builtin_amdgcn_global_load_lds(
                (const __attribute__((address_space(1))) void*)srcB,
                (__attribute__((address_space(3))) void*)(lsB + s * 8), 16, 0, 0);
        }
        __syncthreads();   // loads drained (vmcnt(0) before s_barrier)

        // ---- compute: 2 k-slices of 32, 4x4 16x16 fragments per wave
#pragma unroll
        for (int kk = 0; kk < 2; ++kk) {
            const int kb = kk * 32 + (lane >> 4) * 8;
            bf16x8 a[4], b[4];
#pragma unroll
            for (int mi = 0; mi < 4; ++mi)
                a[mi] = *reinterpret_cast<const bf16x8*>(
                    &lsA[(wm + mi * 16 + (lane & 15)) * TK + kb]);
#pragma unroll
            for (int ni = 0; ni < 4; ++ni)
                b[ni] = *reinterpret_cast<const bf16x8*>(
                    &lsB[(wn + ni * 16 + (lane & 15)) * TK + kb]);
#pragma unroll
            for (int mi = 0; mi < 4; ++mi)
#pragma unroll
                for (int ni = 0; ni < 4; ++ni)
                    acc[mi][ni] = __builtin_amdgcn_mfma_f32_16x16x32_bf16(
                        a[mi], b[ni], acc[mi][ni], 0, 0, 0);
        }
    }

    // ---- epilogue: C/D layout col = lane&15, row = (lane>>4)*4 + r
    const int cn    = n0 + wn + (lane & 15);
    const int rbase = m0 + wm + (lane >> 4) * 4;
#pragma unroll
    for (int mi = 0; mi < 4; ++mi) {
#pragma unroll
        for (int ni = 0; ni < 4; ++ni) {
            const int col = cn + ni * 16;
            const float bv = bias[col];
#pragma unroll
            for (int r = 0; r < 4; ++r) {
                const int row = rbase + mi * 16 + r;
                const float x = acc[mi][ni][r] + bv;
                if (EPI == 0) {
                    const float s = x / (1.0f + __expf(-x));   // silu
                    reinterpret_cast<__hip_bfloat16*>(C)[(size_t)row * N + col] =
                        __float2bfloat16(s);
                } else {
                    reinterpret_cast<float*>(C)[(size_t)row * N + col] = x;
                }
            }
        }
    }
}

// ---------------------------------------------------------------------------
extern "C" void kernel_launch(void* const* d_in, const int* in_sizes, int n_in,
                              void* d_out, int out_size, void* d_ws, size_t ws_size,
                              hipStream_t stream) {
    const int*   tokens = (const int*)d_in[0];
    const float* emb    = (const float*)d_in[1];
    const float* W1     = (const float*)d_in[2];
    const float* b1     = (const float*)d_in[3];
    const float* W2     = (const float*)d_in[4];
    const float* b2     = (const float*)d_in[5];
    float* out = (float*)d_out;

    // workspace layout (bytes)
    char* ws = (char*)d_ws;
    __hip_bfloat16* W2T = (__hip_bfloat16*)(ws);                 // 32000x1024 bf16 = 65,536,000
    __hip_bfloat16* W1T = (__hip_bfloat16*)(ws + 65536000);      // 1024x3072 bf16  =  6,291,456
    __hip_bfloat16* X   = (__hip_bfloat16*)(ws + 71827456);      // 4096x3072 bf16  = 25,165,824
    __hip_bfloat16* H   = (__hip_bfloat16*)(ws + 96993280);      // 4096x1024 bf16  =  8,388,608

    // 1. W2 (1024 x 32000) -> W2T (32000 x 1024) bf16
    transpose_cvt<<<dim3(V_SZ / 32, D_SZ / 32), dim3(32, 8), 0, stream>>>(W2, W2T, D_SZ, V_SZ);
    // 2. W1 (3072 x 1024) -> W1T (1024 x 3072) bf16
    transpose_cvt<<<dim3(D_SZ / 32, KD / 32), dim3(32, 8), 0, stream>>>(W1, W1T, KD, D_SZ);
    // 3. gather ctx embeddings -> X (4096 x 3072) bf16
    gather_cvt<<<M_SZ * KCTX, 256, 0, stream>>>(tokens, emb, X);
    // 4. H = silu(X @ W1 + b1)  (4096 x 1024) bf16
    gemm_bt<0><<<dim3(D_SZ / TN, M_SZ / TM), 256, 0, stream>>>(
        (const unsigned short*)X, (const unsigned short*)W1T, b1, H, M_SZ, D_SZ, KD);
    // 5. logits = H @ W2 + b2  (4096 x 32000) f32
    gemm_bt<1><<<dim3(V_SZ / TN, M_SZ / TM), 256, 0, stream>>>(
        (const unsigned short*)H, (const unsigned short*)W2T, b2, out, M_SZ, V_SZ, D_SZ);
}